// Round 1
// baseline (474.121 us; speedup 1.0000x reference)
//
#include <hip/hip_runtime.h>

typedef unsigned short u16;
typedef __attribute__((ext_vector_type(8))) short short8;
typedef __attribute__((ext_vector_type(4))) float f32x4;
typedef __attribute__((ext_vector_type(4))) u16 u16x4;

#define LOG2E 1.4426950408889634f

static __device__ __forceinline__ float bf2f(u16 u) {
    return __uint_as_float(((unsigned)u) << 16);
}
static __device__ __forceinline__ u16 f2bf(float f) {
    unsigned u = __float_as_uint(f);
    unsigned r = (u + 0x7FFF + ((u >> 16) & 1)) >> 16;
    return (u16)r;
}
static __device__ __forceinline__ f32x4 mfma16(short8 a, short8 b, f32x4 c) {
    return __builtin_amdgcn_mfma_f32_16x16x32_bf16(a, b, c, 0, 0, 0);
}

// ---------------- cast x (fp32 -> bf16), vectorized ----------------
__global__ void cast_x_kernel(const float* __restrict__ x, u16* __restrict__ xb, int n) {
    int i = (blockIdx.x * blockDim.x + threadIdx.x) * 4;
    int stride = gridDim.x * blockDim.x * 4;
    for (; i < n; i += stride) {
        f32x4 v = *(const f32x4*)&x[i];
        u16x4 o;
        o.x = f2bf(v.x); o.y = f2bf(v.y); o.z = f2bf(v.z); o.w = f2bf(v.w);
        *(u16x4*)&xb[i] = o;
    }
}

// ---------------- transpose + cast: src[R][C] fp32 -> dst[C][R] bf16 ----------------
__global__ void transpose_cast_kernel(const float* __restrict__ src, u16* __restrict__ dst,
                                      int R, int C) {
    __shared__ float tile[32][33];
    int c0 = blockIdx.x * 32, r0 = blockIdx.y * 32;
    int tx = threadIdx.x, ty = threadIdx.y;
    int r = r0 + ty, c = c0 + tx;
    if (r < R && c < C) tile[ty][tx] = src[r * C + c];
    __syncthreads();
    int orow = c0 + ty;   // output row = original col
    int oc   = r0 + tx;   // output col = original row
    if (orow < C && oc < R) dst[orow * R + oc] = f2bf(tile[tx][ty]);
}

// ---------------- LoRA-A: xa = (x @ A) * 2.0, bf16 out, all 3 adapters ----------------
__global__ __launch_bounds__(64) void lora_a_kernel(
    const float* __restrict__ x,
    const float* __restrict__ qA, const float* __restrict__ kA, const float* __restrict__ vA,
    u16* __restrict__ xaq, u16* __restrict__ xak, u16* __restrict__ xav) {
    const int r = blockIdx.x;
    const int lane = threadIdx.x;
    float aq[16] = {}, ak[16] = {}, av[16] = {};
    const float* xr = x + (size_t)r * 2048;
    for (int kk = lane; kk < 2048; kk += 64) {
        const float xv = xr[kk];
        const f32x4* q4 = (const f32x4*)(qA + kk * 16);
        const f32x4* k4 = (const f32x4*)(kA + kk * 16);
        const f32x4* v4 = (const f32x4*)(vA + kk * 16);
#pragma unroll
        for (int t = 0; t < 4; ++t) {
            f32x4 a = q4[t], b = k4[t], cc = v4[t];
#pragma unroll
            for (int e = 0; e < 4; ++e) {
                aq[t * 4 + e] += xv * a[e];
                ak[t * 4 + e] += xv * b[e];
                av[t * 4 + e] += xv * cc[e];
            }
        }
    }
#pragma unroll
    for (int j = 0; j < 16; ++j) {
#pragma unroll
        for (int off = 1; off < 64; off <<= 1) {
            aq[j] += __shfl_xor(aq[j], off);
            ak[j] += __shfl_xor(ak[j], off);
            av[j] += __shfl_xor(av[j], off);
        }
    }
    if (lane == 0) {
#pragma unroll
        for (int j = 0; j < 16; ++j) {
            xaq[r * 16 + j] = f2bf(aq[j] * 2.0f);
            xak[r * 16 + j] = f2bf(ak[j] * 2.0f);
            xav[r * 16 + j] = f2bf(av[j] * 2.0f);
        }
    }
}

// ---------------- GEMM: C[M=4096][Nn] = A[4096][2048] @ Bt[Nn][2048]^T (+ LoRA) ----------------
// 128x128 tile, BK=64, 4 waves (2x2), each wave 64x64 via 4x4 16x16x32 MFMA frags.
template <int LORA, int OUTF32>
__global__ __launch_bounds__(256) void gemm_kernel(
    const u16* __restrict__ A, const u16* __restrict__ Bt, void* __restrict__ Cout, int Nn,
    const u16* __restrict__ xa, const u16* __restrict__ LBt) {
    constexpr int K = 2048;
    constexpr int LS = 72;  // padded LDS stride (bf16 elems): 144B rows -> 2-way (free) banking
    __shared__ u16 As[128 * LS];
    __shared__ u16 Bs[128 * LS];
    const int tid = threadIdx.x;
    const int wid = tid >> 6, lane = tid & 63;
    const int mbase = blockIdx.x * 128;
    const int nbase = blockIdx.y * 128;
    const int wrow = (wid >> 1) * 64, wcol = (wid & 1) * 64;
    const int fr = lane & 15, fk = (lane >> 4) * 8;
    const int srow = tid >> 3, soff = (tid & 7) * 8;
    f32x4 acc[4][4] = {};
    const u16* Ag = A + (size_t)mbase * K;
    const u16* Bg = Bt + (size_t)nbase * K;
    for (int kt = 0; kt < K; kt += 64) {
        short8 ar[4], br[4];
#pragma unroll
        for (int i = 0; i < 4; ++i) {
            ar[i] = *(const short8*)&Ag[(size_t)(srow + 32 * i) * K + kt + soff];
            br[i] = *(const short8*)&Bg[(size_t)(srow + 32 * i) * K + kt + soff];
        }
        __syncthreads();
#pragma unroll
        for (int i = 0; i < 4; ++i) {
            *(short8*)&As[(srow + 32 * i) * LS + soff] = ar[i];
            *(short8*)&Bs[(srow + 32 * i) * LS + soff] = br[i];
        }
        __syncthreads();
#pragma unroll
        for (int ks = 0; ks < 2; ++ks) {
            short8 af[4], bfr[4];
#pragma unroll
            for (int i = 0; i < 4; ++i) {
                af[i]  = *(const short8*)&As[(wrow + i * 16 + fr) * LS + ks * 32 + fk];
                bfr[i] = *(const short8*)&Bs[(wcol + i * 16 + fr) * LS + ks * 32 + fk];
            }
#pragma unroll
            for (int mi = 0; mi < 4; ++mi)
#pragma unroll
                for (int ni = 0; ni < 4; ++ni)
                    acc[mi][ni] = mfma16(af[mi], bfr[ni], acc[mi][ni]);
        }
    }
    if (LORA) {
        // one extra K=32 step: cols 0..15 = rank-16 LoRA, cols 16..31 = zero pad
        const int rr = tid >> 1, hh = (tid & 1) * 8;
        short8 xv = *(const short8*)&xa[(mbase + rr) * 16 + hh];
        short8 lv = *(const short8*)&LBt[(nbase + rr) * 16 + hh];
        short8 z = {};
        __syncthreads();
        *(short8*)&As[rr * LS + hh] = xv;
        *(short8*)&As[rr * LS + 16 + hh] = z;
        *(short8*)&Bs[rr * LS + hh] = lv;
        *(short8*)&Bs[rr * LS + 16 + hh] = z;
        __syncthreads();
        short8 af[4], bfr[4];
#pragma unroll
        for (int i = 0; i < 4; ++i) {
            af[i]  = *(const short8*)&As[(wrow + i * 16 + fr) * LS + fk];
            bfr[i] = *(const short8*)&Bs[(wcol + i * 16 + fr) * LS + fk];
        }
#pragma unroll
        for (int mi = 0; mi < 4; ++mi)
#pragma unroll
            for (int ni = 0; ni < 4; ++ni)
                acc[mi][ni] = mfma16(af[mi], bfr[ni], acc[mi][ni]);
    }
    // epilogue: C/D layout col=lane&15, row=(lane>>4)*4+j  [measured m89]
    const int rb = mbase + wrow + ((lane >> 4) << 2);
    const int cb = nbase + wcol + fr;
    if (OUTF32) {
        float* C = (float*)Cout;
#pragma unroll
        for (int mi = 0; mi < 4; ++mi)
#pragma unroll
            for (int j = 0; j < 4; ++j) {
                const size_t ro = (size_t)(rb + mi * 16 + j) * Nn;
#pragma unroll
                for (int ni = 0; ni < 4; ++ni) C[ro + cb + ni * 16] = acc[mi][ni][j];
            }
    } else {
        u16* C = (u16*)Cout;
#pragma unroll
        for (int mi = 0; mi < 4; ++mi)
#pragma unroll
            for (int j = 0; j < 4; ++j) {
                const size_t ro = (size_t)(rb + mi * 16 + j) * Nn;
#pragma unroll
                for (int ni = 0; ni < 4; ++ni) C[ro + cb + ni * 16] = f2bf(acc[mi][ni][j]);
            }
    }
}

// ---------------- RoPE in place on bf16 [4096][width], 4 pairs per thread ----------------
__global__ void rope_kernel(u16* __restrict__ t, const float* __restrict__ cosb,
                            const float* __restrict__ sinb, int width, int shift) {
    int idx = blockIdx.x * blockDim.x + threadIdx.x;
    int base = idx * 8;
    int row = base >> shift;           // /width
    int within = base & (width - 1);
    int d0 = within & 63;
    int i0 = d0 >> 1;                  // pair index, multiple of 4
    int s = row & 1023;                // row % S
    short8 v = *(short8*)&t[base];
    f32x4 cv = *(const f32x4*)&cosb[s * 32 + i0];
    f32x4 sv = *(const f32x4*)&sinb[s * 32 + i0];
#pragma unroll
    for (int p = 0; p < 4; ++p) {
        float x0 = bf2f((u16)v[2 * p]);
        float x1 = bf2f((u16)v[2 * p + 1]);
        float r0 = x0 * cv[p] - x1 * sv[p];
        float r1 = x0 * sv[p] + x1 * cv[p];
        v[2 * p] = (short)f2bf(r0);
        v[2 * p + 1] = (short)f2bf(r1);
    }
    *(short8*)&t[base] = v;
}

// ---------------- causal GQA flash attention ----------------
// grid (qt=16, h=32, b=4), 256 threads = 4 waves, wave w owns q rows [qt*64+w*16, +16)
__global__ __launch_bounds__(256) void attn_kernel(
    const u16* __restrict__ q, const u16* __restrict__ k, const u16* __restrict__ v,
    u16* __restrict__ ctx) {
    __shared__ u16 Ks[64 * 72];
    __shared__ u16 Vt[64 * 72];   // transposed: Vt[d][kv]
    __shared__ u16 Ps[4 * 16 * 72];
    const int qt = blockIdx.x, h = blockIdx.y, b = blockIdx.z;
    const int g = h >> 2;  // kv head
    const int tid = threadIdx.x, wid = tid >> 6, lane = tid & 63;
    const int fr = lane & 15, fk = (lane >> 4) * 8;
    const int qrow0 = qt * 64 + wid * 16;
    short8 qf[2];
    {
        const u16* qp = &q[((size_t)(b * 1024 + qrow0 + fr)) * 2048 + h * 64];
        qf[0] = *(const short8*)&qp[fk];
        qf[1] = *(const short8*)&qp[32 + fk];
    }
    f32x4 o[4] = {};
    float mrow[4] = {-3.0e38f, -3.0e38f, -3.0e38f, -3.0e38f};
    float lrow[4] = {};
    const int sr0 = tid >> 3, so0 = (tid & 7) * 8;
    u16* Pw = &Ps[wid * 16 * 72];
    for (int kt = 0; kt <= qt; ++kt) {
        const u16* kp = &k[((size_t)(b * 1024 + kt * 64)) * 512 + g * 64];
        const u16* vp = &v[((size_t)(b * 1024 + kt * 64)) * 512 + g * 64];
        short8 k0 = *(const short8*)&kp[sr0 * 512 + so0];
        short8 k1 = *(const short8*)&kp[(sr0 + 32) * 512 + so0];
        short8 v0 = *(const short8*)&vp[sr0 * 512 + so0];
        short8 v1 = *(const short8*)&vp[(sr0 + 32) * 512 + so0];
        __syncthreads();   // previous iter's LDS reads done
        *(short8*)&Ks[sr0 * 72 + so0] = k0;
        *(short8*)&Ks[(sr0 + 32) * 72 + so0] = k1;
#pragma unroll
        for (int j = 0; j < 8; ++j) {
            Vt[(so0 + j) * 72 + sr0] = (u16)v0[j];
            Vt[(so0 + j) * 72 + sr0 + 32] = (u16)v1[j];
        }
        __syncthreads();
        // S = Q K^T (16 q-rows x 64 kv-cols per wave)
        f32x4 s[4];
#pragma unroll
        for (int ni = 0; ni < 4; ++ni) {
            f32x4 z = {};
            short8 kf0 = *(const short8*)&Ks[(ni * 16 + fr) * 72 + fk];
            short8 kf1 = *(const short8*)&Ks[(ni * 16 + fr) * 72 + 32 + fk];
            z = mfma16(qf[0], kf0, z);
            z = mfma16(qf[1], kf1, z);
            s[ni] = z;
        }
        const bool diag = (kt == qt);
#pragma unroll
        for (int ni = 0; ni < 4; ++ni)
#pragma unroll
            for (int j = 0; j < 4; ++j) {
                float val = s[ni][j] * 0.125f;
                if (diag) {
                    int col = kt * 64 + ni * 16 + fr;
                    int row = qrow0 + ((lane >> 4) << 2) + j;
                    if (col > row) val = -3.0e38f;
                }
                s[ni][j] = val;
            }
        // online softmax
        float mnew[4], fsc[4], rs[4];
#pragma unroll
        for (int j = 0; j < 4; ++j) {
            float m0 = fmaxf(fmaxf(s[0][j], s[1][j]), fmaxf(s[2][j], s[3][j]));
#pragma unroll
            for (int off = 1; off < 16; off <<= 1) m0 = fmaxf(m0, __shfl_xor(m0, off));
            mnew[j] = fmaxf(mrow[j], m0);
            fsc[j] = exp2f((mrow[j] - mnew[j]) * LOG2E);
            mrow[j] = mnew[j];
            rs[j] = 0.0f;
        }
#pragma unroll
        for (int ni = 0; ni < 4; ++ni)
#pragma unroll
            for (int j = 0; j < 4; ++j) {
                float p = exp2f((s[ni][j] - mnew[j]) * LOG2E);
                s[ni][j] = p;
                rs[j] += p;
            }
#pragma unroll
        for (int j = 0; j < 4; ++j) {
#pragma unroll
            for (int off = 1; off < 16; off <<= 1) rs[j] += __shfl_xor(rs[j], off);
            lrow[j] = lrow[j] * fsc[j] + rs[j];
        }
#pragma unroll
        for (int dn = 0; dn < 4; ++dn)
#pragma unroll
            for (int j = 0; j < 4; ++j) o[dn][j] *= fsc[j];
        // P -> LDS (C-layout scatter), reshape to A-fragment
#pragma unroll
        for (int ni = 0; ni < 4; ++ni)
#pragma unroll
            for (int j = 0; j < 4; ++j)
                Pw[(((lane >> 4) << 2) + j) * 72 + ni * 16 + fr] = f2bf(s[ni][j]);
        __syncthreads();
        // O += P V
#pragma unroll
        for (int ks = 0; ks < 2; ++ks) {
            short8 pf = *(const short8*)&Pw[fr * 72 + ks * 32 + fk];
#pragma unroll
            for (int dn = 0; dn < 4; ++dn) {
                short8 vf = *(const short8*)&Vt[(dn * 16 + fr) * 72 + ks * 32 + fk];
                o[dn] = mfma16(pf, vf, o[dn]);
            }
        }
    }
    float inv[4];
#pragma unroll
    for (int j = 0; j < 4; ++j) inv[j] = 1.0f / lrow[j];
    const int orow = qrow0 + ((lane >> 4) << 2);
    const int ocol = h * 64 + fr;
#pragma unroll
    for (int dn = 0; dn < 4; ++dn)
#pragma unroll
        for (int j = 0; j < 4; ++j)
            ctx[((size_t)(b * 1024 + orow + j)) * 2048 + ocol + dn * 16] = f2bf(o[dn][j] * inv[j]);
}

extern "C" void kernel_launch(void* const* d_in, const int* in_sizes, int n_in,
                              void* d_out, int out_size, void* d_ws, size_t ws_size,
                              hipStream_t stream) {
    const float* x    = (const float*)d_in[0];
    const float* fcos = (const float*)d_in[1];
    const float* fsin = (const float*)d_in[2];
    const float* Wq   = (const float*)d_in[3];
    const float* Wk   = (const float*)d_in[4];
    const float* Wv   = (const float*)d_in[5];
    const float* Wo   = (const float*)d_in[6];
    const float* qA   = (const float*)d_in[7];
    const float* qB   = (const float*)d_in[8];
    const float* kA   = (const float*)d_in[9];
    const float* kB   = (const float*)d_in[10];
    const float* vA   = (const float*)d_in[11];
    const float* vB   = (const float*)d_in[12];
    float* out = (float*)d_out;

    char* ws = (char*)d_ws;
    size_t off = 0;
    auto alloc = [&](size_t bytes) { char* p = ws + off; off += (bytes + 255) & ~(size_t)255; return p; };
    u16* xb   = (u16*)alloc(4096 * 2048 * 2);
    u16* WqT  = (u16*)alloc(2048 * 2048 * 2);
    u16* WkT  = (u16*)alloc(512 * 2048 * 2);
    u16* WvT  = (u16*)alloc(512 * 2048 * 2);
    u16* WoT  = (u16*)alloc(2048 * 2048 * 2);
    u16* qBt  = (u16*)alloc(2048 * 16 * 2);
    u16* kBt  = (u16*)alloc(512 * 16 * 2);
    u16* vBt  = (u16*)alloc(512 * 16 * 2);
    u16* xaq  = (u16*)alloc(4096 * 16 * 2);
    u16* xak  = (u16*)alloc(4096 * 16 * 2);
    u16* xav  = (u16*)alloc(4096 * 16 * 2);
    u16* qbuf = (u16*)alloc(4096 * 2048 * 2);
    u16* kbuf = (u16*)alloc(4096 * 512 * 2);
    u16* vbuf = (u16*)alloc(4096 * 512 * 2);
    u16* ctx  = (u16*)alloc(4096 * 2048 * 2);

    cast_x_kernel<<<2048, 256, 0, stream>>>(x, xb, 4096 * 2048);

    dim3 tb(32, 32);
    transpose_cast_kernel<<<dim3(64, 64), tb, 0, stream>>>(Wq, WqT, 2048, 2048);
    transpose_cast_kernel<<<dim3(16, 64), tb, 0, stream>>>(Wk, WkT, 2048, 512);
    transpose_cast_kernel<<<dim3(16, 64), tb, 0, stream>>>(Wv, WvT, 2048, 512);
    transpose_cast_kernel<<<dim3(64, 64), tb, 0, stream>>>(Wo, WoT, 2048, 2048);
    transpose_cast_kernel<<<dim3(64, 1), tb, 0, stream>>>(qB, qBt, 16, 2048);
    transpose_cast_kernel<<<dim3(16, 1), tb, 0, stream>>>(kB, kBt, 16, 512);
    transpose_cast_kernel<<<dim3(16, 1), tb, 0, stream>>>(vB, vBt, 16, 512);

    lora_a_kernel<<<4096, 64, 0, stream>>>(x, qA, kA, vA, xaq, xak, xav);

    gemm_kernel<1, 0><<<dim3(32, 16), 256, 0, stream>>>(xb, WqT, qbuf, 2048, xaq, qBt);
    gemm_kernel<1, 0><<<dim3(32, 4), 256, 0, stream>>>(xb, WkT, kbuf, 512, xak, kBt);
    gemm_kernel<1, 0><<<dim3(32, 4), 256, 0, stream>>>(xb, WvT, vbuf, 512, xav, vBt);

    rope_kernel<<<4096, 256, 0, stream>>>(qbuf, fcos, fsin, 2048, 11);
    rope_kernel<<<1024, 256, 0, stream>>>(kbuf, fcos, fsin, 512, 9);

    attn_kernel<<<dim3(16, 32, 4), 256, 0, stream>>>(qbuf, kbuf, vbuf, ctx);

    gemm_kernel<0, 1><<<dim3(32, 16), 256, 0, stream>>>(ctx, WoT, out, 2048, nullptr, nullptr);
}